// Round 11
// baseline (705.384 us; speedup 1.0000x reference)
//
#include <hip/hip_runtime.h>

// GCN layer: out = relu(x @ W_self^T + b_self + segment_mean(x[src], dst) @ W_neigh^T)
// N = 100000 nodes, D = 64, E = 1.25M edges.
//
// Pipeline (5 kernels, no CSR):
//   x2bf          : one-time x fp32 -> bf16 (12.8 MB data plane).
//   init_cursor   : cursor[b] = b*CAP (fixed-capacity buckets, no hist/scan).
//   bin_scatter   : LDS-staged radix scatter into 782 buckets of 128 dst-nodes
//                   (block-local hist + scan + contiguous run claim -> mostly
//                   full-line writes, no cross-XCD partial-line churn).
//   bucket_gather : one block per 128-node bucket. fp32 LDS accumulators
//                   (native ds_add_f32), stride-65 rows -> all-32-bank access,
//                   2 lanes/bank = conflict-free. Half-wave per edge, lane k
//                   handles dims k and k+32. Independent iterations, 4 blocks/CU
//                   resident. Mean (deg clip) folded into bf16 write-out.
//   gcn_gemm      : bf16 MFMA (16x16x32), zero LDS; A-frags straight from bf16
//                   xb/aggb; W packed from fp32 (L1-hot); bias+relu fused.

#define BKSH 7                // log2(nodes per bucket)
#define BKN 128               // nodes per bucket
#define CAP 2048              // edge capacity per bucket (mean 1598, +11 sigma)
#define CHUNK 4096            // edges per scatter block
#define SCANN 1024            // scan width (>= NBK = 782)

typedef __attribute__((ext_vector_type(8))) short short8;
typedef __attribute__((ext_vector_type(4))) float floatx4;

// fp32 -> bf16 round-to-nearest-even, branch-free.
static __device__ inline unsigned short f2bf(float f) {
  union { float f; unsigned int u; } v;
  v.f = f;
  unsigned int r = v.u + 0x7FFFu + ((v.u >> 16) & 1u);
  return (unsigned short)(r >> 16);
}

static __device__ inline short8 pack8(float4 a, float4 b) {
  short8 s;
  s[0] = (short)f2bf(a.x); s[1] = (short)f2bf(a.y);
  s[2] = (short)f2bf(a.z); s[3] = (short)f2bf(a.w);
  s[4] = (short)f2bf(b.x); s[5] = (short)f2bf(b.y);
  s[6] = (short)f2bf(b.z); s[7] = (short)f2bf(b.w);
  return s;
}

static __device__ inline float bf2f(unsigned short u) {
  return __uint_as_float((unsigned int)u << 16);
}

__global__ __launch_bounds__(256) void x2bf(const float* __restrict__ x,
                                            unsigned short* __restrict__ xb,
                                            long long n) {
  long long i = ((long long)blockIdx.x * 256 + threadIdx.x) * 8;
  if (i < n) {
    float4 a = *(const float4*)&x[i];
    float4 b = *(const float4*)&x[i + 4];
    *(short8*)&xb[i] = pack8(a, b);
  }
}

__global__ __launch_bounds__(256) void init_cursor(int* __restrict__ cursor, int NBK) {
  int i = blockIdx.x * 256 + threadIdx.x;
  if (i < NBK) cursor[i] = i * CAP;
}

// LDS-staged radix scatter into fixed-capacity bucket regions.
__global__ __launch_bounds__(256) void bin_scatter(const int* __restrict__ src,
                                                   const int* __restrict__ dst,
                                                   int* __restrict__ cursor,
                                                   int* __restrict__ ebuf,
                                                   int E, int NBK) {
  __shared__ int h[SCANN], loff[SCANN], gbase[SCANN];
  __shared__ int sbuf[CHUNK];
  __shared__ int wsum[4];
  int t = threadIdx.x;
  for (int i = t; i < SCANN; i += 256) h[i] = 0;
  __syncthreads();

  int base = blockIdx.x * CHUNK;
  int myd[CHUNK / 256], mys[CHUNK / 256];
#pragma unroll
  for (int i = 0; i < CHUNK / 256; ++i) {
    int e = base + t + 256 * i;  // coalesced
    if (e < E) {
      myd[i] = dst[e];
      mys[i] = src[e];
      atomicAdd(&h[myd[i] >> BKSH], 1);
    } else myd[i] = -1;
  }
  __syncthreads();

  // block exclusive scan of h[0..1023] (4 entries per thread)
  {
    int i0 = t * 4;
    int v0 = h[i0], v1 = h[i0 + 1], v2 = h[i0 + 2], v3 = h[i0 + 3];
    int tot = v0 + v1 + v2 + v3;
    int lane = t & 63, w = t >> 6;
    int inc = tot;
#pragma unroll
    for (int o = 1; o < 64; o <<= 1) {
      int u = __shfl_up(inc, o, 64);
      if (lane >= o) inc += u;
    }
    if (lane == 63) wsum[w] = inc;
    __syncthreads();
    int wex = 0;
    for (int i = 0; i < w; ++i) wex += wsum[i];
    int ex = wex + inc - tot;
    loff[i0] = ex; loff[i0 + 1] = ex + v0;
    loff[i0 + 2] = ex + v0 + v1; loff[i0 + 3] = ex + v0 + v1 + v2;
  }
  __syncthreads();

  // claim contiguous runs in each bucket's fixed region; reuse h as local cursor
  for (int b = t; b < SCANN; b += 256) {
    if (b < NBK && h[b] > 0) gbase[b] = atomicAdd(&cursor[b], h[b]);
    h[b] = 0;
  }
  __syncthreads();

  // LDS bucket-sort of this chunk
#pragma unroll
  for (int i = 0; i < CHUNK / 256; ++i) {
    if (myd[i] >= 0) {
      int b = myd[i] >> BKSH;
      int p = atomicAdd(&h[b], 1);
      sbuf[loff[b] + p] = mys[i] | ((myd[i] & (BKN - 1)) << 17);  // src < 2^17
    }
  }
  __syncthreads();

  // stream each (block,bucket) run out contiguously
  int w = t >> 6, lane = t & 63;
  for (int b = w; b < NBK; b += 4) {
    int c = h[b], lo = loff[b], go = gbase[b];
    for (int j = lane; j < c; j += 64)
      ebuf[go + j] = sbuf[lo + j];
  }
}

// One block per 128-node bucket. fp32 LDS acc, stride 65 dwords/node:
// ds_add addr = n*65 + k (k = lane&31) -> bank (n+k)%32: each half-wave spans
// all 32 banks once; 2 halves = 2 lanes/bank = free. Lane k handles dims k,k+32.
__global__ __launch_bounds__(256) void bucket_gather(const unsigned short* __restrict__ xb,
                                                     const int* __restrict__ cursor,
                                                     const int* __restrict__ ebuf,
                                                     unsigned short* __restrict__ aggb,
                                                     int N) {
  __shared__ float acc[BKN * 65];
  __shared__ int deg[BKN];
  int t = threadIdx.x;
  int b = blockIdx.x;

  for (int i = t; i < BKN * 65; i += 256) acc[i] = 0.f;
  if (t < BKN) deg[t] = 0;
  __syncthreads();

  int s = b * CAP;
  int cnt = cursor[b] - s;       // edges in this bucket
  int lane = t & 63, w = t >> 6;
  int h = lane >> 5, k = lane & 31;

  // wave w handles edge-pairs it = w, w+4, ...; half-wave h takes edge 2*it+h
  for (int it = w; 2 * it < cnt; it += 4) {
    int o = 2 * it + h;
    if (o < cnt) {
      int v = ebuf[s + o];                   // 32-lane broadcast load
      int sn = v & 0x1FFFF;
      int n = (v >> 17) & (BKN - 1);
      const unsigned short* row = xb + (long long)sn * 64;
      float f0 = bf2f(row[k]);
      float f1 = bf2f(row[k + 32]);
      atomicAdd(&acc[n * 65 + k], f0);       // native ds_add_f32, conflict-free
      atomicAdd(&acc[n * 65 + k + 32], f1);
      if (k == 0) atomicAdd(&deg[n], 1);
    }
  }
  __syncthreads();

  // write out bf16 mean rows (coalesced: 32 lanes = one 128B row)
  int nb0 = b << BKSH;
  for (int i = t; i < BKN * 32; i += 256) {
    int n = i >> 5, j = i & 31;
    int node = nb0 + n;
    if (node < N) {
      float dg = (float)deg[n];
      float inv = 1.0f / fmaxf(dg, 1.0f);
      float f0 = acc[n * 65 + 2 * j] * inv;
      float f1 = acc[n * 65 + 2 * j + 1] * inv;
      unsigned int p = ((unsigned int)f2bf(f1) << 16) | (unsigned int)f2bf(f0);
      ((unsigned int*)aggb)[(long long)node * 32 + j] = p;
    }
  }
}

// bf16 MFMA GEMM, zero LDS. Wave w owns nodes [blk*64 + w*16, +16).
// A-frags (X, AGG) load DIRECTLY from bf16 arrays: one dwordx4 per lane per
// 32-k step. B-frags packed from fp32 W (32KB, L1/L2-hot). One accumulator:
// D = Ax*Ws^T + Aagg*Wn^T. C/D: col=lane&15, row=quad*4+reg (HW-verified).
__global__ __launch_bounds__(256) void gcn_gemm(const unsigned short* __restrict__ xb,
                                                const unsigned short* __restrict__ aggb,
                                                const float* __restrict__ Wself,
                                                const float* __restrict__ bself,
                                                const float* __restrict__ Wneigh,
                                                float* __restrict__ out, int N) {
  int lane = threadIdx.x & 63;
  int w = threadIdx.x >> 6;
  int tb = blockIdx.x * 64 + w * 16;
  int m = lane & 15, q = lane >> 4;

  long long rowA = (long long)min(tb + m, N - 1) * 64;
  short8 ax[2], aa[2];
#pragma unroll
  for (int ks = 0; ks < 2; ++ks) {
    ax[ks] = *(const short8*)&xb[rowA + ks * 32 + q * 8];
    aa[ks] = *(const short8*)&aggb[rowA + ks * 32 + q * 8];
  }

#pragma unroll
  for (int nt = 0; nt < 4; ++nt) {
    int ob = nt * 16;
    long long rowB = (long long)(ob + m) * 64;
    floatx4 acc = {0.f, 0.f, 0.f, 0.f};
#pragma unroll
    for (int ks = 0; ks < 2; ++ks) {
      const float* pw = &Wself[rowB + ks * 32 + q * 8];
      short8 bw = pack8(*(const float4*)pw, *(const float4*)(pw + 4));
      acc = __builtin_amdgcn_mfma_f32_16x16x32_bf16(ax[ks], bw, acc, 0, 0, 0);
      const float* pn = &Wneigh[rowB + ks * 32 + q * 8];
      short8 bn = pack8(*(const float4*)pn, *(const float4*)(pn + 4));
      acc = __builtin_amdgcn_mfma_f32_16x16x32_bf16(aa[ks], bn, acc, 0, 0, 0);
    }
    float bias = bself[ob + m];
#pragma unroll
    for (int r = 0; r < 4; ++r) {
      int node = tb + q * 4 + r;
      if (node < N) {
        float v = acc[r] + bias;
        out[(long long)node * 64 + ob + m] = fmaxf(v, 0.f);
      }
    }
  }
}

extern "C" void kernel_launch(void* const* d_in, const int* in_sizes, int n_in,
                              void* d_out, int out_size, void* d_ws, size_t ws_size,
                              hipStream_t stream) {
  const float* x      = (const float*)d_in[0];
  const int*   eidx   = (const int*)d_in[1];
  const float* Wself  = (const float*)d_in[2];
  const float* bself  = (const float*)d_in[3];
  const float* Wneigh = (const float*)d_in[4];
  float* out = (float*)d_out;

  const int N = in_sizes[0] / 64;
  const int E = in_sizes[1] / 2;
  const int* src = eidx;      // edge_index row 0
  const int* dst = eidx + E;  // edge_index row 1
  const int NBK = (N + BKN - 1) / BKN;  // 782 buckets of 128 nodes

  // ws layout: xb[N*64] bf16 | aggb[N*64] bf16 | cursor[NBK] | ebuf[NBK*CAP + slack]
  unsigned short* xb   = (unsigned short*)d_ws;
  unsigned short* aggb = xb + (size_t)N * 64;
  int* cursor = (int*)(aggb + (size_t)N * 64);
  int* ebuf   = cursor + ((NBK + 63) & ~63);

  long long nx = (long long)N * 64;
  x2bf<<<(int)((nx / 8 + 255) / 256), 256, 0, stream>>>(x, xb, nx);
  init_cursor<<<(NBK + 255) / 256, 256, 0, stream>>>(cursor, NBK);

  int cb = (E + CHUNK - 1) / CHUNK;  // 306 scatter blocks
  bin_scatter<<<cb, 256, 0, stream>>>(src, dst, cursor, ebuf, E, NBK);
  bucket_gather<<<NBK, 256, 0, stream>>>(xb, cursor, ebuf, aggb, N);
  gcn_gemm<<<(N + 63) / 64, 256, 0, stream>>>(xb, aggb, Wself, bself, Wneigh, out, N);
}

// Round 12
// 190.926 us; speedup vs baseline: 3.6945x; 3.6945x over previous
//
#include <hip/hip_runtime.h>

// GCN layer: out = relu(x @ W_self^T + b_self + segment_mean(x[src], dst) @ W_neigh^T)
// N = 100000 nodes, D = 64, E = 1.25M edges.
//
// Pipeline (6 kernels):
//   x2bf        : one-time x fp32 -> bf16 (12.8 MB data plane).
//   init_cursor : cursor[b] = b*CAP (fixed-capacity buckets -> no hist/scan).
//   bin_scatter : LDS-staged radix scatter into 98 buckets of 1024 dst-nodes;
//                 block-local int-LDS hist + scan + contiguous run claim ->
//                 full-line writes (no cross-XCD partial-line churn).
//   sb_csr      : one 1024-thread block per bucket (98 blocks): window count ->
//                 block scan -> node-sort into col; emits rowstart/rowcnt.
//                 NOTE: LDS *int* atomics only — LDS fp32 atomicAdd is a CAS
//                 loop on gfx950 and serializes (r3/r11: ~500 µs disasters).
//   gcn_gather  : one wave per node on bf16 rows (128B): 8 edges per dwordx4
//                 instruction, fp32 accumulate, cross-oct shuffle reduce,
//                 mean folded into bf16 write.
//   gcn_gemm    : bf16 MFMA (16x16x32), zero LDS; A-frags straight from bf16
//                 xb/aggb; W packed from fp32 (L1-hot); bias+relu fused.

#define BKSH 10               // log2(nodes per bucket)
#define BKN 1024              // nodes per bucket
#define NBMAX 128             // >= NB = 98
#define CAPE 14336            // edge capacity per bucket (mean 12800, +13 sigma)
#define CHUNK 4096            // edges per scatter block

typedef __attribute__((ext_vector_type(8))) short short8;
typedef __attribute__((ext_vector_type(4))) float floatx4;

// fp32 -> bf16 round-to-nearest-even, branch-free.
static __device__ inline unsigned short f2bf(float f) {
  union { float f; unsigned int u; } v;
  v.f = f;
  unsigned int r = v.u + 0x7FFFu + ((v.u >> 16) & 1u);
  return (unsigned short)(r >> 16);
}

static __device__ inline short8 pack8(float4 a, float4 b) {
  short8 s;
  s[0] = (short)f2bf(a.x); s[1] = (short)f2bf(a.y);
  s[2] = (short)f2bf(a.z); s[3] = (short)f2bf(a.w);
  s[4] = (short)f2bf(b.x); s[5] = (short)f2bf(b.y);
  s[6] = (short)f2bf(b.z); s[7] = (short)f2bf(b.w);
  return s;
}

// unpack 8 bf16 (4 dwords) and accumulate into 8 fp32.
static __device__ inline void add8(float* a, short8 sv) {
  union { short8 s; unsigned int u[4]; } c; c.s = sv;
#pragma unroll
  for (int i = 0; i < 4; ++i) {
    a[2 * i]     += __uint_as_float(c.u[i] << 16);
    a[2 * i + 1] += __uint_as_float(c.u[i] & 0xFFFF0000u);
  }
}

__global__ __launch_bounds__(256) void x2bf(const float* __restrict__ x,
                                            unsigned short* __restrict__ xb,
                                            long long n) {
  long long i = ((long long)blockIdx.x * 256 + threadIdx.x) * 8;
  if (i < n) {
    float4 a = *(const float4*)&x[i];
    float4 b = *(const float4*)&x[i + 4];
    *(short8*)&xb[i] = pack8(a, b);
  }
}

__global__ __launch_bounds__(256) void init_cursor(int* __restrict__ cursor, int NB) {
  int i = blockIdx.x * 256 + threadIdx.x;
  if (i < NB) cursor[i] = i * CAPE;
}

// LDS-staged radix scatter into fixed-capacity bucket regions.
__global__ __launch_bounds__(256) void bin_scatter(const int* __restrict__ src,
                                                   const int* __restrict__ dst,
                                                   int* __restrict__ cursor,
                                                   int* __restrict__ ebuf, int E, int NB) {
  __shared__ int h[NBMAX], loff[NBMAX], gbase[NBMAX];
  __shared__ int sbuf[CHUNK];
  int t = threadIdx.x;
  if (t < NBMAX) h[t] = 0;
  __syncthreads();

  int base = blockIdx.x * CHUNK;
  int myd[CHUNK / 256], mys[CHUNK / 256];
#pragma unroll
  for (int i = 0; i < CHUNK / 256; ++i) {
    int e = base + t + 256 * i;  // coalesced
    if (e < E) {
      myd[i] = dst[e];
      mys[i] = src[e];
      atomicAdd(&h[myd[i] >> BKSH], 1);
    } else myd[i] = -1;
  }
  __syncthreads();

  if (t < 64) {  // wave 0: exclusive scan of h[0..127]
    int i0 = 2 * t, i1 = 2 * t + 1;
    int v0 = h[i0], v1 = h[i1];
    int s = v0 + v1, inc = s;
#pragma unroll
    for (int off = 1; off < 64; off <<= 1) {
      int u = __shfl_up(inc, off, 64);
      if (t >= off) inc += u;
    }
    int ex = inc - s;
    loff[i0] = ex; loff[i1] = ex + v0;
  }
  __syncthreads();

  if (t < NB) {
    if (h[t] > 0) gbase[t] = atomicAdd(&cursor[t], h[t]);  // claim contiguous run
  }
  if (t < NBMAX) h[t] = 0;  // reuse as local cursor
  __syncthreads();

#pragma unroll
  for (int i = 0; i < CHUNK / 256; ++i) {
    if (myd[i] >= 0) {
      int b = myd[i] >> BKSH;
      int p = atomicAdd(&h[b], 1);           // LDS int atomic: native, fast
      sbuf[loff[b] + p] = mys[i] | ((myd[i] & (BKN - 1)) << 17);  // src < 2^17
    }
  }
  __syncthreads();

  int w = t >> 6, lane = t & 63;
  for (int b = w; b < NB; b += 4) {
    int c = h[b], lo = loff[b], go = gbase[b];
    for (int j = lane; j < c; j += 64)
      ebuf[go + j] = sbuf[lo + j];
  }
}

// One 1024-thread block per 1024-node bucket (98 blocks, window read stays
// block-private — no cross-XCD re-fetch). Count -> block scan -> node-sort.
__global__ __launch_bounds__(1024) void sb_csr(const int* __restrict__ cursor,
                                               const int* __restrict__ ebuf,
                                               int* __restrict__ col,
                                               int* __restrict__ rowstart,
                                               int* __restrict__ rowcnt, int N) {
  __shared__ int cnt[BKN], off[BKN];
  __shared__ int wsum[16];
  int b = blockIdx.x, t = threadIdx.x;
  int s = b * CAPE, e = cursor[b];
  cnt[t] = 0;
  __syncthreads();
  for (int j = s + t; j < e; j += 1024)
    atomicAdd(&cnt[(ebuf[j] >> 17) & (BKN - 1)], 1);
  __syncthreads();

  // block exclusive scan over 1024 (1 per thread, 16 waves)
  int v = cnt[t];
  int lane = t & 63, w = t >> 6;
  int inc = v;
#pragma unroll
  for (int o = 1; o < 64; o <<= 1) {
    int u = __shfl_up(inc, o, 64);
    if (lane >= o) inc += u;
  }
  if (lane == 63) wsum[w] = inc;
  __syncthreads();
  if (t < 16) {
    int s0 = wsum[t], incw = s0;
#pragma unroll
    for (int o = 1; o < 16; o <<= 1) {
      int u = __shfl_up(incw, o, 64);
      if (t >= o) incw += u;
    }
    wsum[t] = incw - s0;
  }
  __syncthreads();
  int ex = wsum[w] + inc - v;
  off[t] = ex;
  int node = (b << BKSH) + t;
  if (node < N) { rowstart[node] = s + ex; rowcnt[node] = v; }
  __syncthreads();
  cnt[t] = 0;  // reuse as cursor
  __syncthreads();
  for (int j = s + t; j < e; j += 1024) {
    int vv = ebuf[j];
    int nl = (vv >> 17) & (BKN - 1);
    int p = atomicAdd(&cnt[nl], 1);
    col[s + off[nl] + p] = vv & 0x1FFFF;  // node-sorted src, block-private lines
  }
}

// One wave per node on bf16 rows (128B). Oct o handles edges j = s+o, s+o+8...;
// one dwordx4 instruction covers 8 edges (1KB). fp32 accumulate, 3-round
// cross-oct shuffle reduce, bf16 agg write (mean folded).
__global__ __launch_bounds__(256) void gcn_gather(const unsigned short* __restrict__ xb,
                                                  const int* __restrict__ rowstart,
                                                  const int* __restrict__ rowcnt,
                                                  const int* __restrict__ col,
                                                  unsigned short* __restrict__ aggb,
                                                  int N) {
  int gid = blockIdx.x * 256 + threadIdx.x;
  int node = gid >> 6;
  if (node >= N) return;
  int lane = threadIdx.x & 63;
  int o = lane >> 3, d = lane & 7;
  int s = rowstart[node], c = rowcnt[node], e = s + c;

  float a[8] = {0.f, 0.f, 0.f, 0.f, 0.f, 0.f, 0.f, 0.f};
  float b2[8] = {0.f, 0.f, 0.f, 0.f, 0.f, 0.f, 0.f, 0.f};
  int j = s + o;
  for (; j + 8 < e; j += 16) {  // 16 edges in flight per wave
    int c0 = col[j], c1 = col[j + 8];
    short8 v0 = *(const short8*)&xb[(long long)c0 * 64 + d * 8];
    short8 v1 = *(const short8*)&xb[(long long)c1 * 64 + d * 8];
    add8(a, v0);
    add8(b2, v1);
  }
  for (; j < e; j += 8) {
    short8 v = *(const short8*)&xb[(long long)col[j] * 64 + d * 8];
    add8(a, v);
  }
#pragma unroll
  for (int k = 0; k < 8; ++k) a[k] += b2[k];

#pragma unroll
  for (int m = 8; m <= 32; m <<= 1) {
#pragma unroll
    for (int k = 0; k < 8; ++k) a[k] += __shfl_xor(a[k], m, 64);
  }

  if (o == 0) {
    float inv = 1.0f / fmaxf((float)c, 1.0f);
    short8 r;
#pragma unroll
    for (int k = 0; k < 8; ++k) r[k] = (short)f2bf(a[k] * inv);
    *(short8*)&aggb[(long long)node * 64 + d * 8] = r;  // 8 lanes x 16B = 128B
  }
}

// bf16 MFMA GEMM, zero LDS. Wave w owns nodes [blk*64 + w*16, +16).
// A-frags load DIRECTLY from bf16 arrays; B-frags packed from fp32 W (L1-hot).
// One accumulator: D = Ax*Ws^T + Aagg*Wn^T. C/D: col=lane&15, row=quad*4+reg.
__global__ __launch_bounds__(256) void gcn_gemm(const unsigned short* __restrict__ xb,
                                                const unsigned short* __restrict__ aggb,
                                                const float* __restrict__ Wself,
                                                const float* __restrict__ bself,
                                                const float* __restrict__ Wneigh,
                                                float* __restrict__ out, int N) {
  int lane = threadIdx.x & 63;
  int w = threadIdx.x >> 6;
  int tb = blockIdx.x * 64 + w * 16;
  int m = lane & 15, q = lane >> 4;

  long long rowA = (long long)min(tb + m, N - 1) * 64;
  short8 ax[2], aa[2];
#pragma unroll
  for (int ks = 0; ks < 2; ++ks) {
    ax[ks] = *(const short8*)&xb[rowA + ks * 32 + q * 8];
    aa[ks] = *(const short8*)&aggb[rowA + ks * 32 + q * 8];
  }

#pragma unroll
  for (int nt = 0; nt < 4; ++nt) {
    int ob = nt * 16;
    long long rowB = (long long)(ob + m) * 64;
    floatx4 acc = {0.f, 0.f, 0.f, 0.f};
#pragma unroll
    for (int ks = 0; ks < 2; ++ks) {
      const float* pw = &Wself[rowB + ks * 32 + q * 8];
      short8 bw = pack8(*(const float4*)pw, *(const float4*)(pw + 4));
      acc = __builtin_amdgcn_mfma_f32_16x16x32_bf16(ax[ks], bw, acc, 0, 0, 0);
      const float* pn = &Wneigh[rowB + ks * 32 + q * 8];
      short8 bn = pack8(*(const float4*)pn, *(const float4*)(pn + 4));
      acc = __builtin_amdgcn_mfma_f32_16x16x32_bf16(aa[ks], bn, acc, 0, 0, 0);
    }
    float bias = bself[ob + m];
#pragma unroll
    for (int r = 0; r < 4; ++r) {
      int node = tb + q * 4 + r;
      if (node < N) {
        float v = acc[r] + bias;
        out[(long long)node * 64 + ob + m] = fmaxf(v, 0.f);
      }
    }
  }
}

extern "C" void kernel_launch(void* const* d_in, const int* in_sizes, int n_in,
                              void* d_out, int out_size, void* d_ws, size_t ws_size,
                              hipStream_t stream) {
  const float* x      = (const float*)d_in[0];
  const int*   eidx   = (const int*)d_in[1];
  const float* Wself  = (const float*)d_in[2];
  const float* bself  = (const float*)d_in[3];
  const float* Wneigh = (const float*)d_in[4];
  float* out = (float*)d_out;

  const int N = in_sizes[0] / 64;
  const int E = in_sizes[1] / 2;
  const int* src = eidx;      // edge_index row 0
  const int* dst = eidx + E;  // edge_index row 1
  const int NB = (N + BKN - 1) / BKN;  // 98 buckets of 1024 nodes

  // ws layout: xb[N*64] bf16 | aggb[N*64] bf16 | cursor[128] | rowstart[N]
  //            | rowcnt[N] | ebuf[NB*CAPE] | col[E]   (~37 MB)
  unsigned short* xb   = (unsigned short*)d_ws;
  unsigned short* aggb = xb + (size_t)N * 64;
  int* cursor   = (int*)(aggb + (size_t)N * 64);
  int* rowstart = cursor + NBMAX;
  int* rowcnt   = rowstart + N;
  int* ebuf     = rowcnt + N;
  int* col      = ebuf + (size_t)NB * CAPE;

  long long nx = (long long)N * 64;
  x2bf<<<(int)((nx / 8 + 255) / 256), 256, 0, stream>>>(x, xb, nx);
  init_cursor<<<1, 256, 0, stream>>>(cursor, NB);

  int cb = (E + CHUNK - 1) / CHUNK;  // 306 scatter blocks
  bin_scatter<<<cb, 256, 0, stream>>>(src, dst, cursor, ebuf, E, NB);
  sb_csr<<<NB, 1024, 0, stream>>>(cursor, ebuf, col, rowstart, rowcnt, N);
  gcn_gather<<<(int)((nx + 255) / 256), 256, 0, stream>>>(xb, rowstart, rowcnt, col, aggb, N);
  gcn_gemm<<<(N + 63) / 64, 256, 0, stream>>>(xb, aggb, Wself, bself, Wneigh, out, N);
}